// Round 1
// baseline (438.613 us; speedup 1.0000x reference)
//
#include <hip/hip_runtime.h>
#include <math.h>

// Problem constants (fixed by setup_inputs): B=16, H=W=1024.
constexpr int Wd = 1024;
constexpr int Hd = 1024;
constexpr int HW = Wd * Hd;          // 1<<20
constexpr float EPSF = 1e-7f;
// total pixels = 16 * 2^20 = 2^24; loss = sum(per_pix) / (H*W) / B = sum / 2^24
constexpr float INV_TOTAL = 1.0f / 16777216.0f;

__global__ __launch_bounds__(256) void conf_loss_kernel(
    const float* __restrict__ of,   // (B, 3, H, W) fp32
    const int*   __restrict__ tgt,  // (B, H, W) int32
    float*       __restrict__ out)  // scalar
{
    const int gid = blockIdx.x * blockDim.x + threadIdx.x;  // one float4 (4 pixels)
    const int p0  = gid << 2;                // global pixel index of first of 4
    const int b   = p0 >> 20;                // / HW
    const int rem = p0 & (HW - 1);
    const int i   = rem >> 10;               // row
    const int j   = rem & (Wd - 1);          // col of first pixel (multiple of 4)

    const float4* of4 = (const float4*)of;
    const int4*   t4  = (const int4*)tgt;

    const int baseU = b * 3 * HW + rem;      // max ~5.03e7, fits int32
    const float4 u0 = of4[(baseU           ) >> 2];
    const float4 u1 = of4[(baseU +     HW  ) >> 2];
    const float4 fv = of4[(baseU + 2 * HW  ) >> 2];
    const int4   tv = t4[(b * HW + rem) >> 2];

    const float fi = (float)i;
    const float us[4] = {u0.x, u0.y, u0.z, u0.w};
    const float vs[4] = {u1.x, u1.y, u1.z, u1.w};
    const float fs[4] = {fv.x, fv.y, fv.z, fv.w};
    const int   ts[4] = {tv.x, tv.y, tv.z, tv.w};

    float sum = 0.0f;
#pragma unroll
    for (int k = 0; k < 4; ++k) {
        int x = (int)floorf(us[k] + (float)(j + k));
        int y = (int)floorf(vs[k] + fi);
        x = min(max(x, 0), Wd - 1);
        y = min(max(y, 0), Hd - 1);
        int t = ts[k];
        t = (t == -1) ? 0 : t;
        int hs = tgt[b * HW + y * Wd + x];   // gather — L1/L2 hit in practice
        hs = (hs == -1) ? 0 : hs;
        const float val = (t == hs) ? (fs[k] + EPSF) : (1.0f - fs[k] + EPSF);
        sum -= __logf(val);
    }

    // wave-64 butterfly reduction
#pragma unroll
    for (int off = 32; off > 0; off >>= 1)
        sum += __shfl_down(sum, off, 64);

    __shared__ float lsum[4];                // 256 threads = 4 waves
    const int lane = threadIdx.x & 63;
    const int wv   = threadIdx.x >> 6;
    if (lane == 0) lsum[wv] = sum;
    __syncthreads();
    if (threadIdx.x == 0) {
        const float s = lsum[0] + lsum[1] + lsum[2] + lsum[3];
        atomicAdd(out, s * INV_TOTAL);
    }
}

extern "C" void kernel_launch(void* const* d_in, const int* in_sizes, int n_in,
                              void* d_out, int out_size, void* d_ws, size_t ws_size,
                              hipStream_t stream) {
    const float* of  = (const float*)d_in[0];
    const int*   tgt = (const int*)d_in[1];
    float*       out = (float*)d_out;

    // d_out is poisoned with 0xAA before every timed launch — zero it on-stream.
    hipMemsetAsync(out, 0, sizeof(float), stream);

    // 16*2^20 pixels / 4 per thread / 256 per block = 16384 blocks
    conf_loss_kernel<<<16384, 256, 0, stream>>>(of, tgt, out);
}

// Round 2
// 314.735 us; speedup vs baseline: 1.3936x; 1.3936x over previous
//
#include <hip/hip_runtime.h>
#include <math.h>

// Problem constants (fixed by setup_inputs): B=16, H=W=1024.
constexpr int Wd = 1024;
constexpr int Hd = 1024;
constexpr int HW = Wd * Hd;              // 1<<20
constexpr int NPIX = 16 * HW;            // 2^24 pixels
constexpr int NGRP = NPIX / 4;           // 2^22 float4 groups
constexpr float EPSF = 1e-7f;
constexpr float INV_TOTAL = 1.0f / 16777216.0f;  // 1/(B*H*W)

constexpr int NBLK = 2048;               // 8 blocks/CU on 256 CUs
constexpr int NTHR = 256;
constexpr int NITER = NGRP / (NBLK * NTHR);  // = 8, exact, no tail

__global__ __launch_bounds__(256) void conf_loss_partial(
    const float* __restrict__ of,    // (B, 3, H, W) fp32
    const int*   __restrict__ tgt,   // (B, H, W) int32
    float*       __restrict__ partial)  // NBLK floats
{
    const float4* of4 = (const float4*)of;
    const int4*   t4  = (const int4*)tgt;
    const int gid0 = blockIdx.x * NTHR + threadIdx.x;

    float sum = 0.0f;
#pragma unroll
    for (int it = 0; it < NITER; ++it) {
        const int g   = gid0 + it * (NBLK * NTHR);  // float4-group index
        const int p0  = g << 2;                      // first pixel of group
        const int b   = p0 >> 20;                    // / HW
        const int rem = p0 & (HW - 1);
        const int i   = rem >> 10;                   // row
        const int j   = rem & (Wd - 1);              // col (multiple of 4)

        const int baseU = b * 3 * HW + rem;
        const float4 u0 = of4[(baseU          ) >> 2];
        const float4 u1 = of4[(baseU +     HW ) >> 2];
        const float4 fv = of4[(baseU + 2 * HW ) >> 2];
        const int4   tv = t4[(b * HW + rem) >> 2];

        const float fi = (float)i;
        const float us[4] = {u0.x, u0.y, u0.z, u0.w};
        const float vs[4] = {u1.x, u1.y, u1.z, u1.w};
        const float fs[4] = {fv.x, fv.y, fv.z, fv.w};
        const int   ts[4] = {tv.x, tv.y, tv.z, tv.w};

#pragma unroll
        for (int k = 0; k < 4; ++k) {
            int x = (int)floorf(us[k] + (float)(j + k));
            int y = (int)floorf(vs[k] + fi);
            x = min(max(x, 0), Wd - 1);
            y = min(max(y, 0), Hd - 1);
            int t = ts[k];
            t = (t == -1) ? 0 : t;
            int hs = tgt[b * HW + y * Wd + x];  // near-self gather, L1/L2 hit
            hs = (hs == -1) ? 0 : hs;
            const float val = (t == hs) ? (fs[k] + EPSF) : (1.0f - fs[k] + EPSF);
            sum -= __logf(val);
        }
    }

    // wave-64 reduction
#pragma unroll
    for (int off = 32; off > 0; off >>= 1)
        sum += __shfl_down(sum, off, 64);

    __shared__ float lsum[4];                // 256 threads = 4 waves
    const int lane = threadIdx.x & 63;
    const int wv   = threadIdx.x >> 6;
    if (lane == 0) lsum[wv] = sum;
    __syncthreads();
    if (threadIdx.x == 0)
        partial[blockIdx.x] = lsum[0] + lsum[1] + lsum[2] + lsum[3];
}

__global__ __launch_bounds__(256) void conf_loss_final(
    const float* __restrict__ partial, float* __restrict__ out)
{
    float s = 0.0f;
#pragma unroll
    for (int it = 0; it < NBLK / NTHR; ++it)   // 8 each
        s += partial[it * NTHR + threadIdx.x];

#pragma unroll
    for (int off = 32; off > 0; off >>= 1)
        s += __shfl_down(s, off, 64);

    __shared__ float lsum[4];
    const int lane = threadIdx.x & 63;
    const int wv   = threadIdx.x >> 6;
    if (lane == 0) lsum[wv] = s;
    __syncthreads();
    if (threadIdx.x == 0)
        out[0] = (lsum[0] + lsum[1] + lsum[2] + lsum[3]) * INV_TOTAL;
}

extern "C" void kernel_launch(void* const* d_in, const int* in_sizes, int n_in,
                              void* d_out, int out_size, void* d_ws, size_t ws_size,
                              hipStream_t stream) {
    const float* of  = (const float*)d_in[0];
    const int*   tgt = (const int*)d_in[1];
    float*       out = (float*)d_out;
    float*       partial = (float*)d_ws;     // NBLK * 4 B = 8 KB scratch

    conf_loss_partial<<<NBLK, NTHR, 0, stream>>>(of, tgt, partial);
    conf_loss_final<<<1, NTHR, 0, stream>>>(partial, out);
}

// Round 3
// 298.170 us; speedup vs baseline: 1.4710x; 1.0556x over previous
//
#include <hip/hip_runtime.h>
#include <math.h>

// Problem constants (fixed by setup_inputs): B=16, H=W=1024.
constexpr int Wd = 1024;
constexpr int Hd = 1024;
constexpr int HW = Wd * Hd;              // 1<<20
constexpr int NPIX = 16 * HW;            // 2^24 pixels
constexpr int NGRP = NPIX / 4;           // 2^22 float4 groups
constexpr float EPSF = 1e-7f;
constexpr float INV_TOTAL = 1.0f / 16777216.0f;  // 1/(B*H*W)

constexpr int NBLK = 2048;               // 8 blocks/CU on 256 CUs
constexpr int NTHR = 256;
constexpr int NITER = NGRP / (NBLK * NTHR);  // = 8, exact, no tail

__global__ __launch_bounds__(256) void conf_loss_partial(
    const float* __restrict__ of,    // (B, 3, H, W) fp32
    const int*   __restrict__ tgt,   // (B, H, W) int32
    float*       __restrict__ partial)  // NBLK floats
{
    const float4* of4 = (const float4*)of;
    const int4*   t4  = (const int4*)tgt;
    const int gid0 = blockIdx.x * NTHR + threadIdx.x;

    float sum = 0.0f;
#pragma unroll
    for (int it = 0; it < NITER; ++it) {
        const int g   = gid0 + it * (NBLK * NTHR);  // float4-group index
        const int p0  = g << 2;                      // first pixel of group
        const int b   = p0 >> 20;                    // / HW
        const int rem = p0 & (HW - 1);
        const int i   = rem >> 10;                   // row
        const int j   = rem & (Wd - 1);              // col (multiple of 4)

        const int baseU = b * 3 * HW + rem;
        const float4 u0 = of4[(baseU          ) >> 2];
        const float4 u1 = of4[(baseU +     HW ) >> 2];
        const float4 fv = of4[(baseU + 2 * HW ) >> 2];

        const float fi = (float)i;
        const float us[4] = {u0.x, u0.y, u0.z, u0.w};
        const float vs[4] = {u1.x, u1.y, u1.z, u1.w};
        const float fs[4] = {fv.x, fv.y, fv.z, fv.w};

        int xs[4], ys[4];
        bool self = true;
#pragma unroll
        for (int k = 0; k < 4; ++k) {
            int x = (int)floorf(us[k] + (float)(j + k));
            int y = (int)floorf(vs[k] + fi);
            x = min(max(x, 0), Wd - 1);
            y = min(max(y, 0), Hd - 1);
            xs[k] = x; ys[k] = y;
            self = self && (x == j + k) && (y == i);
        }

        if (__all(self)) {
            // Every lane's gather is its own pixel -> H_s == tmp_target
            // element-wise -> mask true regardless of target values.
            // target load provably unused: skip it.
#pragma unroll
            for (int k = 0; k < 4; ++k)
                sum -= __logf(fs[k] + EPSF);
        } else {
            const int4 tv = t4[(b * HW + rem) >> 2];
            const int ts[4] = {tv.x, tv.y, tv.z, tv.w};
#pragma unroll
            for (int k = 0; k < 4; ++k) {
                int t = ts[k];
                t = (t == -1) ? 0 : t;
                int hs = tgt[b * HW + ys[k] * Wd + xs[k]];
                hs = (hs == -1) ? 0 : hs;
                const float val = (t == hs) ? (fs[k] + EPSF)
                                            : (1.0f - fs[k] + EPSF);
                sum -= __logf(val);
            }
        }
    }

    // wave-64 reduction
#pragma unroll
    for (int off = 32; off > 0; off >>= 1)
        sum += __shfl_down(sum, off, 64);

    __shared__ float lsum[4];                // 256 threads = 4 waves
    const int lane = threadIdx.x & 63;
    const int wv   = threadIdx.x >> 6;
    if (lane == 0) lsum[wv] = sum;
    __syncthreads();
    if (threadIdx.x == 0)
        partial[blockIdx.x] = lsum[0] + lsum[1] + lsum[2] + lsum[3];
}

__global__ __launch_bounds__(256) void conf_loss_final(
    const float* __restrict__ partial, float* __restrict__ out)
{
    float s = 0.0f;
#pragma unroll
    for (int it = 0; it < NBLK / NTHR; ++it)   // 8 each
        s += partial[it * NTHR + threadIdx.x];

#pragma unroll
    for (int off = 32; off > 0; off >>= 1)
        s += __shfl_down(s, off, 64);

    __shared__ float lsum[4];
    const int lane = threadIdx.x & 63;
    const int wv   = threadIdx.x >> 6;
    if (lane == 0) lsum[wv] = s;
    __syncthreads();
    if (threadIdx.x == 0)
        out[0] = (lsum[0] + lsum[1] + lsum[2] + lsum[3]) * INV_TOTAL;
}

extern "C" void kernel_launch(void* const* d_in, const int* in_sizes, int n_in,
                              void* d_out, int out_size, void* d_ws, size_t ws_size,
                              hipStream_t stream) {
    const float* of  = (const float*)d_in[0];
    const int*   tgt = (const int*)d_in[1];
    float*       out = (float*)d_out;
    float*       partial = (float*)d_ws;     // NBLK * 4 B = 8 KB scratch

    conf_loss_partial<<<NBLK, NTHR, 0, stream>>>(of, tgt, partial);
    conf_loss_final<<<1, NTHR, 0, stream>>>(partial, out);
}